// Round 7
// baseline (142.925 us; speedup 1.0000x reference)
//
#include <hip/hip_runtime.h>
#include <math.h>

#define NB 4
#define NN 10000
#define NE 160000
#define DIN 256   // C+H
#define DOUT 512  // 4H

typedef short bf16x8 __attribute__((ext_vector_type(8)));
typedef float f32x4 __attribute__((ext_vector_type(4)));

__device__ inline unsigned short f2bf(float f) {
    unsigned int u = __float_as_uint(f);
    unsigned int r = (u + 0x7fffu + ((u >> 16) & 1u)) >> 16;
    return (unsigned short)r;
}
__device__ inline float bf2f(unsigned short u) {
    return __uint_as_float(((unsigned int)u) << 16);
}

// ---------------- pack W^T bf16 [512][256] + degree accumulation ----------------
__global__ __launch_bounds__(256) void k_packdeg(
        const float* __restrict__ Wi, const float* __restrict__ Wf,
        const float* __restrict__ Wo, const float* __restrict__ Wg,
        const float* __restrict__ bi, const float* __restrict__ bf,
        const float* __restrict__ bo, const float* __restrict__ bg,
        const int* __restrict__ ei, const float* __restrict__ ew,
        float* __restrict__ deg, int* __restrict__ cnt,
        unsigned short* __restrict__ Wt, float* __restrict__ bcat) {
    int bid = blockIdx.x;
    if (bid < 512) {
        int i = bid * 256 + threadIdx.x;  // 0..131071
        int n = i >> 8, k = i & 255;
        int g = n >> 7, j = n & 127;
        const float* W = (g == 0) ? Wi : (g == 1) ? Wf : (g == 2) ? Wo : Wg;
        Wt[i] = f2bf(W[k * 128 + j]);
        if (i < DOUT) {
            int gg = i >> 7, jj = i & 127;
            const float* bb = (gg == 0) ? bi : (gg == 1) ? bf : (gg == 2) ? bo : bg;
            bcat[i] = bb[jj];
        }
    } else {
        int e = (bid - 512) * 256 + threadIdx.x;  // exactly 160000
        int dst = ei[NE + e];
        atomicAdd(&deg[dst], ew[e]);
        atomicAdd(&cnt[dst], 1);
    }
}

// block 0: dinv = rsqrt(deg+1) + single-block scan of cnt
// blocks 1..1250: x||h -> bf16 NODE-major xhb[n*4+b][256]
__global__ __launch_bounds__(1024) void k_scancvt(
        float* __restrict__ deg, const int* __restrict__ cnt, int* __restrict__ offsets,
        const float* __restrict__ x, const float* __restrict__ h,
        unsigned short* __restrict__ xhb) {
    int t = threadIdx.x;
    int bid = blockIdx.x;
    if (bid == 0) {
        for (int i = t; i < NN; i += 1024) {
            deg[i] = rsqrtf(deg[i] + 1.0f);
        }
        __shared__ int wsum[16];
        int base = t * 10;
        int loc[10];
        int s = 0;
#pragma unroll
        for (int i = 0; i < 10; ++i) {
            int idx = base + i;
            int v = (idx < NN) ? cnt[idx] : 0;
            loc[i] = s;
            s += v;
        }
        int lane = t & 63, w = t >> 6;
        int inc = s;
        for (int o = 1; o < 64; o <<= 1) {
            int u = __shfl_up(inc, o);
            if (lane >= o) inc += u;
        }
        if (lane == 63) wsum[w] = inc;
        __syncthreads();
        if (t < 16) {
            int v = wsum[t];
            for (int o = 1; o < 16; o <<= 1) {
                int u = __shfl_up(v, o);
                if (t >= o) v += u;
            }
            wsum[t] = v;
        }
        __syncthreads();
        int wave_excl = (w > 0) ? wsum[w - 1] : 0;
        int thread_excl = wave_excl + inc - s;
#pragma unroll
        for (int i = 0; i < 10; ++i) {
            int idx = base + i;
            if (idx < NN) offsets[idx] = thread_excl + loc[i];
        }
        if (t == 0) offsets[NN] = wsum[15];
    } else {
        int id = (bid - 1) * 1024 + t;  // 0 .. 1,279,999
        int f8 = id * 8;
        int row = f8 >> 8;        // n*4 + b
        int col = f8 & 255;
        int n = row >> 2, b = row & 3;
        const float* src = ((col >> 7) ? h : x) + ((size_t)b * NN + n) * 128 + (col & 127);
        float4 v0 = *(const float4*)src;
        float4 v1 = *(const float4*)(src + 4);
        bf16x8 o;
        o[0] = (short)f2bf(v0.x); o[1] = (short)f2bf(v0.y);
        o[2] = (short)f2bf(v0.z); o[3] = (short)f2bf(v0.w);
        o[4] = (short)f2bf(v1.x); o[5] = (short)f2bf(v1.y);
        o[6] = (short)f2bf(v1.z); o[7] = (short)f2bf(v1.w);
        *(bf16x8*)(xhb + (size_t)f8) = o;
    }
}

__global__ __launch_bounds__(256) void k_fill(const int* __restrict__ ei,
                                              const float* __restrict__ ew,
                                              const float* __restrict__ dinv,
                                              const int* __restrict__ offsets,
                                              int* cursor, int2* __restrict__ ebuf) {
    int e = blockIdx.x * 256 + threadIdx.x;  // exactly 160000
    int src = ei[e], dst = ei[NE + e];
    float norm = dinv[src] * ew[e] * dinv[dst];
    int pos = offsets[dst] + atomicAdd(&cursor[dst], 1);
    ebuf[pos] = make_int2(src, __float_as_int(norm));
}

// ---------------- FUSED agg + MFMA GEMM + LSTM ----------------
// 1250 blocks x 512 thr (8 waves). Wave wid aggregates node n = bid*8+wid (all 4 batches)
// into a 32x256 bf16 A-tile in LDS (row m = b*8 + wid, XOR-swizzled). One barrier.
// Then wave w computes j' = w*16 .. +16 for all 4 gates x 32 rows: B-frags streamed from
// L2-resident Wt, 64 MFMA, fused LSTM epilogue with prefetched c_in.
__global__ __launch_bounds__(512) void k_fused(const unsigned short* __restrict__ xhb,
                                               const float* __restrict__ dinv,
                                               const int* __restrict__ offsets,
                                               const int2* __restrict__ ebuf,
                                               const unsigned short* __restrict__ Wt,
                                               const float* __restrict__ bcat,
                                               const float* __restrict__ c_in,
                                               float* __restrict__ out) {
    __shared__ __align__(16) unsigned short sA[32 * 256];  // 16KB
    int t = threadIdx.x;
    int lane = t & 63, wid = t >> 6;   // wave 0..7
    int nbase = blockIdx.x * 8;
    int n = nbase + wid;

    // ---- agg phase: lane: b = lane>>4, 16 feats at ks = (lane&15)*16 ----
    int l16 = lane * 16;  // element offset into 1024-elem node row (2KB)
    float acc[16];
#pragma unroll
    for (int i = 0; i < 16; ++i) acc[i] = 0.f;

#define EACC(E)                                                         \
    {                                                                   \
        float w = __int_as_float((E).y);                                \
        const unsigned short* p = xhb + (size_t)(E).x * 1024 + l16;     \
        bf16x8 v0 = *(const bf16x8*)p;                                  \
        bf16x8 v1 = *(const bf16x8*)(p + 8);                            \
        acc[0] = fmaf(w, bf2f((unsigned short)v0[0]), acc[0]);          \
        acc[1] = fmaf(w, bf2f((unsigned short)v0[1]), acc[1]);          \
        acc[2] = fmaf(w, bf2f((unsigned short)v0[2]), acc[2]);          \
        acc[3] = fmaf(w, bf2f((unsigned short)v0[3]), acc[3]);          \
        acc[4] = fmaf(w, bf2f((unsigned short)v0[4]), acc[4]);          \
        acc[5] = fmaf(w, bf2f((unsigned short)v0[5]), acc[5]);          \
        acc[6] = fmaf(w, bf2f((unsigned short)v0[6]), acc[6]);          \
        acc[7] = fmaf(w, bf2f((unsigned short)v0[7]), acc[7]);          \
        acc[8] = fmaf(w, bf2f((unsigned short)v1[0]), acc[8]);          \
        acc[9] = fmaf(w, bf2f((unsigned short)v1[1]), acc[9]);          \
        acc[10] = fmaf(w, bf2f((unsigned short)v1[2]), acc[10]);        \
        acc[11] = fmaf(w, bf2f((unsigned short)v1[3]), acc[11]);        \
        acc[12] = fmaf(w, bf2f((unsigned short)v1[4]), acc[12]);        \
        acc[13] = fmaf(w, bf2f((unsigned short)v1[5]), acc[13]);        \
        acc[14] = fmaf(w, bf2f((unsigned short)v1[6]), acc[14]);        \
        acc[15] = fmaf(w, bf2f((unsigned short)v1[7]), acc[15]);        \
    }

    int beg = offsets[n], end = offsets[n + 1];
    int j = beg;
    for (; j + 4 <= end; j += 4) {
        int2 e0 = ebuf[j + 0], e1 = ebuf[j + 1], e2 = ebuf[j + 2], e3 = ebuf[j + 3];
        EACC(e0); EACC(e1); EACC(e2); EACC(e3);
    }
    for (; j < end; ++j) {
        int2 e = ebuf[j];
        EACC(e);
    }
    {   // self loop: weight dinv[n]^2
        float di = dinv[n];
        int2 es = make_int2(n, __float_as_int(di * di));
        EACC(es);
    }

    // write A-tile row m = b*8 + wid (b = lane>>4); 32B at byte col (lane&15)*32, swizzled
    {
        int m = ((lane >> 4) << 3) + wid;
        int colb = (lane & 15) << 5;
        int swz = (m & 7) << 4;
        bf16x8 o0, o1;
#pragma unroll
        for (int i = 0; i < 8; ++i) { o0[i] = (short)f2bf(acc[i]); o1[i] = (short)f2bf(acc[8 + i]); }
        *(bf16x8*)((char*)sA + m * 512 + (colb ^ swz)) = o0;
        *(bf16x8*)((char*)sA + m * 512 + ((colb + 16) ^ swz)) = o1;
    }

    // ---- prefetch c_in + biases (independent of LDS) ----
    int lr = lane & 15, lk = lane >> 4;
    int jj = wid * 16 + lr;   // 0..127
    float b_i = bcat[jj], b_f = bcat[128 + jj], b_o = bcat[256 + jj], b_g = bcat[384 + jj];
    float cv[2][4];
#pragma unroll
    for (int mi = 0; mi < 2; ++mi)
#pragma unroll
        for (int r = 0; r < 4; ++r) {
            int m = mi * 16 + lk * 4 + r;
            cv[mi][r] = c_in[((size_t)(m >> 3) * NN + nbase + (m & 7)) * 128 + jj];
        }

    __syncthreads();  // A-tile resident

    // ---- GEMM phase: acc2[mi][g] over 8 k-steps ----
    f32x4 acc2[2][4];
#pragma unroll
    for (int mi = 0; mi < 2; ++mi)
#pragma unroll
        for (int g = 0; g < 4; ++g) acc2[mi][g] = (f32x4)0.f;

    const unsigned short* Bp = Wt + (size_t)jj * 256 + lk * 8;  // + g*128*256 + kb*32
    int aswz = (lr & 7) << 4;
#pragma unroll
    for (int kb = 0; kb < 8; ++kb) {
        int koff = (kb << 6) + (lk << 4);
        bf16x8 a0 = *(const bf16x8*)((const char*)sA + lr * 512 + (koff ^ aswz));
        bf16x8 a1 = *(const bf16x8*)((const char*)sA + (16 + lr) * 512 + (koff ^ aswz));
        bf16x8 b0 = *(const bf16x8*)(Bp + (size_t)0 * 32768 + kb * 32);
        bf16x8 b1 = *(const bf16x8*)(Bp + (size_t)1 * 32768 + kb * 32);
        bf16x8 b2 = *(const bf16x8*)(Bp + (size_t)2 * 32768 + kb * 32);
        bf16x8 b3 = *(const bf16x8*)(Bp + (size_t)3 * 32768 + kb * 32);
        acc2[0][0] = __builtin_amdgcn_mfma_f32_16x16x32_bf16(a0, b0, acc2[0][0], 0, 0, 0);
        acc2[0][1] = __builtin_amdgcn_mfma_f32_16x16x32_bf16(a0, b1, acc2[0][1], 0, 0, 0);
        acc2[0][2] = __builtin_amdgcn_mfma_f32_16x16x32_bf16(a0, b2, acc2[0][2], 0, 0, 0);
        acc2[0][3] = __builtin_amdgcn_mfma_f32_16x16x32_bf16(a0, b3, acc2[0][3], 0, 0, 0);
        acc2[1][0] = __builtin_amdgcn_mfma_f32_16x16x32_bf16(a1, b0, acc2[1][0], 0, 0, 0);
        acc2[1][1] = __builtin_amdgcn_mfma_f32_16x16x32_bf16(a1, b1, acc2[1][1], 0, 0, 0);
        acc2[1][2] = __builtin_amdgcn_mfma_f32_16x16x32_bf16(a1, b2, acc2[1][2], 0, 0, 0);
        acc2[1][3] = __builtin_amdgcn_mfma_f32_16x16x32_bf16(a1, b3, acc2[1][3], 0, 0, 0);
    }

    // ---- fused LSTM epilogue: lane holds all 4 gates for (m, jj) ----
#pragma unroll
    for (int mi = 0; mi < 2; ++mi) {
#pragma unroll
        for (int r = 0; r < 4; ++r) {
            int m = mi * 16 + lk * 4 + r;
            float vi = acc2[mi][0][r] + b_i;
            float vf = acc2[mi][1][r] + b_f;
            float vo = acc2[mi][2][r] + b_o;
            float vg = acc2[mi][3][r] + b_g;
            float ig = 1.f / (1.f + __expf(-vi));
            float fg = 1.f / (1.f + __expf(-vf));
            float og = 1.f / (1.f + __expf(-vo));
            float gg = 1.f - 2.f / (__expf(2.f * vg) + 1.f);
            float cn = fg * cv[mi][r] + ig * gg;
            float tc = 1.f - 2.f / (__expf(2.f * cn) + 1.f);
            size_t o = ((size_t)(m >> 3) * NN + nbase + (m & 7)) * 128 + jj;
            out[o] = og * tc;
            out[(size_t)NB * NN * 128 + o] = cn;
        }
    }
}

// ---------------- launch ----------------

extern "C" void kernel_launch(void* const* d_in, const int* in_sizes, int n_in,
                              void* d_out, int out_size, void* d_ws, size_t ws_size,
                              hipStream_t stream) {
    const float* x = (const float*)d_in[0];
    const float* h = (const float*)d_in[1];
    const float* c = (const float*)d_in[2];
    const int* ei = (const int*)d_in[3];
    const float* ew = (const float*)d_in[4];
    const float* Wi = (const float*)d_in[5];
    const float* bi = (const float*)d_in[6];
    const float* Wf = (const float*)d_in[7];
    const float* bf = (const float*)d_in[8];
    const float* Wo = (const float*)d_in[9];
    const float* bo = (const float*)d_in[10];
    const float* Wg = (const float*)d_in[11];
    const float* bg = (const float*)d_in[12];
    float* out = (float*)d_out;

    char* ws = (char*)d_ws;
    size_t off = 0;
    auto alloc = [&](size_t bytes) {
        void* p = ws + off;
        off = (off + bytes + 255) & ~(size_t)255;
        return p;
    };
    float* deg = (float*)alloc((size_t)NN * 4);    // 40192B padded; becomes dinv
    int* cnt = (int*)alloc((size_t)NN * 4);        // 40192B
    int* cursor = (int*)alloc((size_t)NN * 4);     // 40192B  (deg,cnt,cursor contiguous)
    int* offsets = (int*)alloc((size_t)(NN + 1) * 4);
    float* bcat = (float*)alloc((size_t)DOUT * 4);
    unsigned short* Wt = (unsigned short*)alloc((size_t)DOUT * DIN * 2);
    int2* ebuf = (int2*)alloc((size_t)NE * 8);
    unsigned short* xhb = (unsigned short*)alloc((size_t)NN * 4 * DIN * 2);  // node-major [n][b][k]

    hipMemsetAsync(deg, 0, 3 * 40192, stream);  // deg, cnt, cursor -> 0

    hipLaunchKernelGGL(k_packdeg, dim3(1137), dim3(256), 0, stream,
                       Wi, Wf, Wo, Wg, bi, bf, bo, bg, ei, ew, deg, cnt, Wt, bcat);
    hipLaunchKernelGGL(k_scancvt, dim3(1251), dim3(1024), 0, stream,
                       deg, cnt, offsets, x, h, xhb);
    hipLaunchKernelGGL(k_fill, dim3(625), dim3(256), 0, stream,
                       ei, ew, deg, offsets, cursor, ebuf);
    hipLaunchKernelGGL(k_fused, dim3(1250), dim3(512), 0, stream,
                       xhb, deg, offsets, ebuf, Wt, bcat, c, out);
}

// Round 8
// 134.330 us; speedup vs baseline: 1.0640x; 1.0640x over previous
//
#include <hip/hip_runtime.h>
#include <math.h>

#define NB 4
#define NN 10000
#define NE 160000
#define DIN 256   // C+H
#define DOUT 512  // 4H

typedef short bf16x8 __attribute__((ext_vector_type(8)));
typedef float f32x4 __attribute__((ext_vector_type(4)));

#define GLOAD_LDS16(g, l) \
    __builtin_amdgcn_global_load_lds((const __attribute__((address_space(1))) void*)(g), \
                                     (__attribute__((address_space(3))) void*)(l), 16, 0, 0)

__device__ inline unsigned short f2bf(float f) {
    unsigned int u = __float_as_uint(f);
    unsigned int r = (u + 0x7fffu + ((u >> 16) & 1u)) >> 16;
    return (unsigned short)r;
}
__device__ inline float bf2f(unsigned short u) {
    return __uint_as_float(((unsigned int)u) << 16);
}

// ---------------- pack Wt2[g][kb][lk][j][8] bf16 + degree accumulation ----------------
// Wt2 linear i = ((((g*8+kb)*4+lk)*128 + j)*8 + e)  <->  W_g[kb*32+lk*8+e][j]
__global__ __launch_bounds__(256) void k_packdeg(
        const float* __restrict__ Wi, const float* __restrict__ Wf,
        const float* __restrict__ Wo, const float* __restrict__ Wg,
        const float* __restrict__ bi, const float* __restrict__ bf,
        const float* __restrict__ bo, const float* __restrict__ bg,
        const int* __restrict__ ei, const float* __restrict__ ew,
        float* __restrict__ deg, int* __restrict__ cnt,
        unsigned short* __restrict__ Wt2, float* __restrict__ bcat) {
    int bid = blockIdx.x;
    if (bid < 512) {
        int i = bid * 256 + threadIdx.x;  // 0..131071
        int e = i & 7;
        int j = (i >> 3) & 127;
        int lk = (i >> 10) & 3;
        int kb = (i >> 12) & 7;
        int g = i >> 15;
        const float* W = (g == 0) ? Wi : (g == 1) ? Wf : (g == 2) ? Wo : Wg;
        Wt2[i] = f2bf(W[(kb * 32 + lk * 8 + e) * 128 + j]);
        if (i < DOUT) {
            int gg = i >> 7, jj = i & 127;
            const float* bb = (gg == 0) ? bi : (gg == 1) ? bf : (gg == 2) ? bo : bg;
            bcat[i] = bb[jj];
        }
    } else {
        int e = (bid - 512) * 256 + threadIdx.x;  // exactly 160000
        int dst = ei[NE + e];
        atomicAdd(&deg[dst], ew[e]);
        atomicAdd(&cnt[dst], 1);
    }
}

// block 0: dinv = rsqrt(deg+1) + single-block scan of cnt
// blocks 1..1250: x||h -> bf16 NODE-major xhb[n*4+b][256]
__global__ __launch_bounds__(1024) void k_scancvt(
        float* __restrict__ deg, const int* __restrict__ cnt, int* __restrict__ offsets,
        const float* __restrict__ x, const float* __restrict__ h,
        unsigned short* __restrict__ xhb) {
    int t = threadIdx.x;
    int bid = blockIdx.x;
    if (bid == 0) {
        for (int i = t; i < NN; i += 1024) {
            deg[i] = rsqrtf(deg[i] + 1.0f);
        }
        __shared__ int wsum[16];
        int base = t * 10;
        int loc[10];
        int s = 0;
#pragma unroll
        for (int i = 0; i < 10; ++i) {
            int idx = base + i;
            int v = (idx < NN) ? cnt[idx] : 0;
            loc[i] = s;
            s += v;
        }
        int lane = t & 63, w = t >> 6;
        int inc = s;
        for (int o = 1; o < 64; o <<= 1) {
            int u = __shfl_up(inc, o);
            if (lane >= o) inc += u;
        }
        if (lane == 63) wsum[w] = inc;
        __syncthreads();
        if (t < 16) {
            int v = wsum[t];
            for (int o = 1; o < 16; o <<= 1) {
                int u = __shfl_up(v, o);
                if (t >= o) v += u;
            }
            wsum[t] = v;
        }
        __syncthreads();
        int wave_excl = (w > 0) ? wsum[w - 1] : 0;
        int thread_excl = wave_excl + inc - s;
#pragma unroll
        for (int i = 0; i < 10; ++i) {
            int idx = base + i;
            if (idx < NN) offsets[idx] = thread_excl + loc[i];
        }
        if (t == 0) offsets[NN] = wsum[15];
    } else {
        int id = (bid - 1) * 1024 + t;  // 0 .. 1,279,999
        int f8 = id * 8;
        int row = f8 >> 8;        // n*4 + b
        int col = f8 & 255;
        int n = row >> 2, b = row & 3;
        const float* src = ((col >> 7) ? h : x) + ((size_t)b * NN + n) * 128 + (col & 127);
        float4 v0 = *(const float4*)src;
        float4 v1 = *(const float4*)(src + 4);
        bf16x8 o;
        o[0] = (short)f2bf(v0.x); o[1] = (short)f2bf(v0.y);
        o[2] = (short)f2bf(v0.z); o[3] = (short)f2bf(v0.w);
        o[4] = (short)f2bf(v1.x); o[5] = (short)f2bf(v1.y);
        o[6] = (short)f2bf(v1.z); o[7] = (short)f2bf(v1.w);
        *(bf16x8*)(xhb + (size_t)f8) = o;
    }
}

__global__ __launch_bounds__(256) void k_fill(const int* __restrict__ ei,
                                              const float* __restrict__ ew,
                                              const float* __restrict__ dinv,
                                              const int* __restrict__ offsets,
                                              int* cursor, int2* __restrict__ ebuf) {
    int e = blockIdx.x * 256 + threadIdx.x;  // exactly 160000
    int src = ei[e], dst = ei[NE + e];
    float norm = dinv[src] * ew[e] * dinv[dst];
    int pos = offsets[dst] + atomicAdd(&cursor[dst], 1);
    ebuf[pos] = make_int2(src, __float_as_int(norm));
}

// ---------------- aggregation, XCD-sliced by (batch, k-half) ----------------
// bid&7 -> xcd -> (b = xcd>>1, kh = xcd&1). Slice slab = 10000 x 256B = 2.5MB -> L2-resident.
// Wave = one node; lane-halves process 2 edges in parallel (8B/lane, 256B/edge);
// __shfl_xor(32) combines halves.
__global__ __launch_bounds__(512) void k_agg(const unsigned short* __restrict__ xhb,
                                             const float* __restrict__ dinv,
                                             const int* __restrict__ offsets,
                                             const int2* __restrict__ ebuf,
                                             unsigned short* __restrict__ aggb) {
    int t = threadIdx.x;
    int lane = t & 63, wid = t >> 6;
    int bid = blockIdx.x;
    int xcd = bid & 7;
    int b = xcd >> 1, kh = xcd & 1;
    int n = (bid >> 3) * 8 + wid;
    int eh = lane >> 5;            // edge parity
    int f4 = (lane & 31) << 2;     // feat offset within 128-half

    const unsigned short* base = xhb + (size_t)b * 256 + kh * 128 + f4;  // + src*1024
    float a0 = 0.f, a1 = 0.f, a2 = 0.f, a3 = 0.f;

#define EACC(E)                                                     \
    {                                                               \
        float w = __int_as_float((E).y);                            \
        ushort4 v = *(const ushort4*)(base + (size_t)(E).x * 1024); \
        a0 = fmaf(w, bf2f(v.x), a0);                                \
        a1 = fmaf(w, bf2f(v.y), a1);                                \
        a2 = fmaf(w, bf2f(v.z), a2);                                \
        a3 = fmaf(w, bf2f(v.w), a3);                                \
    }

    int beg = offsets[n], end = offsets[n + 1];
    int j = beg + eh;
    for (; j + 2 < end; j += 4) {
        int2 e0 = ebuf[j], e1 = ebuf[j + 2];
        EACC(e0); EACC(e1);
    }
    for (; j < end; j += 2) {
        int2 e = ebuf[j];
        EACC(e);
    }
    // combine edge-parity halves
    a0 += __shfl_xor(a0, 32);
    a1 += __shfl_xor(a1, 32);
    a2 += __shfl_xor(a2, 32);
    a3 += __shfl_xor(a3, 32);
    {   // self loop (same value in both halves; only eh==0 writes)
        float di = dinv[n];
        float w = di * di;
        ushort4 v = *(const ushort4*)(base + (size_t)n * 1024);
        a0 = fmaf(w, bf2f(v.x), a0);
        a1 = fmaf(w, bf2f(v.y), a1);
        a2 = fmaf(w, bf2f(v.z), a2);
        a3 = fmaf(w, bf2f(v.w), a3);
    }
    if (eh == 0) {
        ushort4 o;
        o.x = f2bf(a0); o.y = f2bf(a1); o.z = f2bf(a2); o.w = f2bf(a3);
        *(ushort4*)(aggb + ((size_t)b * NN + n) * 256 + kh * 128 + f4) = o;
    }
}

// ---------------- MFMA GEMM (40000x256 @ 256^T x 512) + fused LSTM gates ----------------
// 256 thr / 4 waves, __launch_bounds__(256,2) -> 256 VGPR budget. Block = 64 rows x 64 j.
// A staged once in 32KB LDS (swizzled source). Wave owns 16 j x 4 gates: B = 128 VGPR
// loaded once from coalesced Wt2; acc 4mi x 4g; 128 MFMA/wave; one barrier; fused LSTM.
__global__ __launch_bounds__(256, 2) void k_gemm(const unsigned short* __restrict__ aggb,
                                                 const unsigned short* __restrict__ Wt2,
                                                 const float* __restrict__ bcat,
                                                 const float* __restrict__ c_in,
                                                 float* __restrict__ out) {
    __shared__ __align__(16) unsigned short sA[64 * 256];  // 32KB
    int t = threadIdx.x;
    int lane = t & 63, wid = t >> 6;
    int lr = lane & 15, lk = lane >> 4;
    int bid = blockIdx.x;
    int rb = bid >> 1, jb = bid & 1;
    int rowbase = rb * 64;
    int jj = jb * 64 + wid * 16 + lr;  // 0..127

    // stage A: 64 rows x 512B, swizzled global source -> linear LDS
#pragma unroll
    for (int i = 0; i < 8; ++i) {
        int idx = i * 256 + t;
        int row = idx >> 5;
        int cb = (idx & 31) << 4;
        const char* g = (const char*)aggb + (size_t)(rowbase + row) * 512 + (cb ^ ((row & 7) << 4));
        char* l = (char*)sA + (size_t)(i * 256 + wid * 64) * 16;
        GLOAD_LDS16(g, l);
    }

    // B fragments to registers: fully-coalesced Wt2 reads (L2-hot, 32KB/wave)
    bf16x8 breg[4][8];
#pragma unroll
    for (int g = 0; g < 8; ++g) {  // flatten: g2 = g>>1... keep simple 4x8
    }
#pragma unroll
    for (int g = 0; g < 4; ++g)
#pragma unroll
        for (int kb = 0; kb < 8; ++kb)
            breg[g][kb] = *(const bf16x8*)(Wt2 + ((size_t)((g * 8 + kb) * 4 + lk) * 128 + jj) * 8);

    float b_i = bcat[jj], b_f = bcat[128 + jj], b_o = bcat[256 + jj], b_g = bcat[384 + jj];

    __syncthreads();  // A resident

    f32x4 acc[4][4];
#pragma unroll
    for (int mi = 0; mi < 4; ++mi)
#pragma unroll
        for (int g = 0; g < 4; ++g) acc[mi][g] = (f32x4)0.f;

    int aswz = (lr & 7) << 4;
#pragma unroll
    for (int kb = 0; kb < 8; ++kb) {
        int koff = (kb << 6) + (lk << 4);
#pragma unroll
        for (int mi = 0; mi < 4; ++mi) {
            bf16x8 a = *(const bf16x8*)((const char*)sA + (mi * 16 + lr) * 512 + (koff ^ aswz));
            acc[mi][0] = __builtin_amdgcn_mfma_f32_16x16x32_bf16(a, breg[0][kb], acc[mi][0], 0, 0, 0);
            acc[mi][1] = __builtin_amdgcn_mfma_f32_16x16x32_bf16(a, breg[1][kb], acc[mi][1], 0, 0, 0);
            acc[mi][2] = __builtin_amdgcn_mfma_f32_16x16x32_bf16(a, breg[2][kb], acc[mi][2], 0, 0, 0);
            acc[mi][3] = __builtin_amdgcn_mfma_f32_16x16x32_bf16(a, breg[3][kb], acc[mi][3], 0, 0, 0);
        }
    }

    // fused LSTM epilogue: lane holds all 4 gates for (row, jj)
#pragma unroll
    for (int mi = 0; mi < 4; ++mi) {
#pragma unroll
        for (int r = 0; r < 4; ++r) {
            int row = rowbase + mi * 16 + lk * 4 + r;
            size_t o = (size_t)row * 128 + jj;
            float vi = acc[mi][0][r] + b_i;
            float vf = acc[mi][1][r] + b_f;
            float vo = acc[mi][2][r] + b_o;
            float vg = acc[mi][3][r] + b_g;
            float ig = 1.f / (1.f + __expf(-vi));
            float fg = 1.f / (1.f + __expf(-vf));
            float og = 1.f / (1.f + __expf(-vo));
            float gg = 1.f - 2.f / (__expf(2.f * vg) + 1.f);
            float cn = fg * c_in[o] + ig * gg;
            float tc = 1.f - 2.f / (__expf(2.f * cn) + 1.f);
            out[o] = og * tc;
            out[(size_t)NB * NN * 128 + o] = cn;
        }
    }
}

// ---------------- launch ----------------

extern "C" void kernel_launch(void* const* d_in, const int* in_sizes, int n_in,
                              void* d_out, int out_size, void* d_ws, size_t ws_size,
                              hipStream_t stream) {
    const float* x = (const float*)d_in[0];
    const float* h = (const float*)d_in[1];
    const float* c = (const float*)d_in[2];
    const int* ei = (const int*)d_in[3];
    const float* ew = (const float*)d_in[4];
    const float* Wi = (const float*)d_in[5];
    const float* bi = (const float*)d_in[6];
    const float* Wf = (const float*)d_in[7];
    const float* bf = (const float*)d_in[8];
    const float* Wo = (const float*)d_in[9];
    const float* bo = (const float*)d_in[10];
    const float* Wg = (const float*)d_in[11];
    const float* bg = (const float*)d_in[12];
    float* out = (float*)d_out;

    char* ws = (char*)d_ws;
    size_t off = 0;
    auto alloc = [&](size_t bytes) {
        void* p = ws + off;
        off = (off + bytes + 255) & ~(size_t)255;
        return p;
    };
    float* deg = (float*)alloc((size_t)NN * 4);    // 40192B padded; becomes dinv
    int* cnt = (int*)alloc((size_t)NN * 4);        // 40192B
    int* cursor = (int*)alloc((size_t)NN * 4);     // 40192B  (deg,cnt,cursor contiguous)
    int* offsets = (int*)alloc((size_t)(NN + 1) * 4);
    float* bcat = (float*)alloc((size_t)DOUT * 4);
    unsigned short* Wt2 = (unsigned short*)alloc((size_t)DOUT * DIN * 2);
    int2* ebuf = (int2*)alloc((size_t)NE * 8);
    unsigned short* xhb = (unsigned short*)alloc((size_t)NN * 4 * DIN * 2);    // node-major [n][b][k]
    unsigned short* aggb = (unsigned short*)alloc((size_t)NB * NN * DIN * 2);  // batch-major [b*NN+n][k]

    hipMemsetAsync(deg, 0, 3 * 40192, stream);  // deg, cnt, cursor -> 0

    hipLaunchKernelGGL(k_packdeg, dim3(1137), dim3(256), 0, stream,
                       Wi, Wf, Wo, Wg, bi, bf, bo, bg, ei, ew, deg, cnt, Wt2, bcat);
    hipLaunchKernelGGL(k_scancvt, dim3(1251), dim3(1024), 0, stream,
                       deg, cnt, offsets, x, h, xhb);
    hipLaunchKernelGGL(k_fill, dim3(625), dim3(256), 0, stream,
                       ei, ew, deg, offsets, cursor, ebuf);
    hipLaunchKernelGGL(k_agg, dim3(10000), dim3(512), 0, stream,
                       xhb, deg, offsets, ebuf, aggb);
    hipLaunchKernelGGL(k_gemm, dim3(1250), dim3(256), 0, stream,
                       aggb, Wt2, bcat, c, out);
}

// Round 9
// 128.984 us; speedup vs baseline: 1.1081x; 1.0414x over previous
//
#include <hip/hip_runtime.h>
#include <math.h>

#define NB 4
#define NN 10000
#define NE 160000
#define DIN 256   // C+H
#define DOUT 512  // 4H

typedef short bf16x8 __attribute__((ext_vector_type(8)));
typedef float f32x4 __attribute__((ext_vector_type(4)));

#define GLOAD_LDS16(g, l) \
    __builtin_amdgcn_global_load_lds((const __attribute__((address_space(1))) void*)(g), \
                                     (__attribute__((address_space(3))) void*)(l), 16, 0, 0)

__device__ inline unsigned short f2bf(float f) {
    unsigned int u = __float_as_uint(f);
    unsigned int r = (u + 0x7fffu + ((u >> 16) & 1u)) >> 16;
    return (unsigned short)r;
}
__device__ inline float bf2f(unsigned short u) {
    return __uint_as_float(((unsigned int)u) << 16);
}

// ---------------- pack Wt2[g][kb][lk][j][8] bf16 + degree accumulation ----------------
__global__ __launch_bounds__(256) void k_packdeg(
        const float* __restrict__ Wi, const float* __restrict__ Wf,
        const float* __restrict__ Wo, const float* __restrict__ Wg,
        const float* __restrict__ bi, const float* __restrict__ bf,
        const float* __restrict__ bo, const float* __restrict__ bg,
        const int* __restrict__ ei, const float* __restrict__ ew,
        float* __restrict__ deg, int* __restrict__ cnt,
        unsigned short* __restrict__ Wt2, float* __restrict__ bcat) {
    int bid = blockIdx.x;
    if (bid < 512) {
        int i = bid * 256 + threadIdx.x;  // 0..131071
        int e = i & 7;
        int j = (i >> 3) & 127;
        int lk = (i >> 10) & 3;
        int kb = (i >> 12) & 7;
        int g = i >> 15;
        const float* W = (g == 0) ? Wi : (g == 1) ? Wf : (g == 2) ? Wo : Wg;
        Wt2[i] = f2bf(W[(kb * 32 + lk * 8 + e) * 128 + j]);
        if (i < DOUT) {
            int gg = i >> 7, jj = i & 127;
            const float* bb = (gg == 0) ? bi : (gg == 1) ? bf : (gg == 2) ? bo : bg;
            bcat[i] = bb[jj];
        }
    } else {
        int e = (bid - 512) * 256 + threadIdx.x;  // exactly 160000
        int dst = ei[NE + e];
        atomicAdd(&deg[dst], ew[e]);
        atomicAdd(&cnt[dst], 1);
    }
}

// block 0: dinv = rsqrt(deg+1) + single-block scan of cnt
// blocks 1..1250: x||h -> bf16 NODE-major xhb[n*4+b][256]
__global__ __launch_bounds__(1024) void k_scancvt(
        float* __restrict__ deg, const int* __restrict__ cnt, int* __restrict__ offsets,
        const float* __restrict__ x, const float* __restrict__ h,
        unsigned short* __restrict__ xhb) {
    int t = threadIdx.x;
    int bid = blockIdx.x;
    if (bid == 0) {
        for (int i = t; i < NN; i += 1024) {
            deg[i] = rsqrtf(deg[i] + 1.0f);
        }
        __shared__ int wsum[16];
        int base = t * 10;
        int loc[10];
        int s = 0;
#pragma unroll
        for (int i = 0; i < 10; ++i) {
            int idx = base + i;
            int v = (idx < NN) ? cnt[idx] : 0;
            loc[i] = s;
            s += v;
        }
        int lane = t & 63, w = t >> 6;
        int inc = s;
        for (int o = 1; o < 64; o <<= 1) {
            int u = __shfl_up(inc, o);
            if (lane >= o) inc += u;
        }
        if (lane == 63) wsum[w] = inc;
        __syncthreads();
        if (t < 16) {
            int v = wsum[t];
            for (int o = 1; o < 16; o <<= 1) {
                int u = __shfl_up(v, o);
                if (t >= o) v += u;
            }
            wsum[t] = v;
        }
        __syncthreads();
        int wave_excl = (w > 0) ? wsum[w - 1] : 0;
        int thread_excl = wave_excl + inc - s;
#pragma unroll
        for (int i = 0; i < 10; ++i) {
            int idx = base + i;
            if (idx < NN) offsets[idx] = thread_excl + loc[i];
        }
        if (t == 0) offsets[NN] = wsum[15];
    } else {
        int id = (bid - 1) * 1024 + t;  // 0 .. 1,279,999
        int f8 = id * 8;
        int row = f8 >> 8;        // n*4 + b
        int col = f8 & 255;
        int n = row >> 2, b = row & 3;
        const float* src = ((col >> 7) ? h : x) + ((size_t)b * NN + n) * 128 + (col & 127);
        float4 v0 = *(const float4*)src;
        float4 v1 = *(const float4*)(src + 4);
        bf16x8 o;
        o[0] = (short)f2bf(v0.x); o[1] = (short)f2bf(v0.y);
        o[2] = (short)f2bf(v0.z); o[3] = (short)f2bf(v0.w);
        o[4] = (short)f2bf(v1.x); o[5] = (short)f2bf(v1.y);
        o[6] = (short)f2bf(v1.z); o[7] = (short)f2bf(v1.w);
        *(bf16x8*)(xhb + (size_t)f8) = o;
    }
}

__global__ __launch_bounds__(256) void k_fill(const int* __restrict__ ei,
                                              const float* __restrict__ ew,
                                              const float* __restrict__ dinv,
                                              const int* __restrict__ offsets,
                                              int* cursor, int2* __restrict__ ebuf) {
    int e = blockIdx.x * 256 + threadIdx.x;  // exactly 160000
    int src = ei[e], dst = ei[NE + e];
    float norm = dinv[src] * ew[e] * dinv[dst];
    int pos = offsets[dst] + atomicAdd(&cursor[dst], 1);
    ebuf[pos] = make_int2(src, __float_as_int(norm));
}

// ---------------- aggregation, XCD-sliced by (batch, k-half), deep-pipelined ----------------
// bid&7 -> (b = xcd>>1, kh = xcd&1): slice slab = 10000 x 256B = 2.5MB -> L2-resident.
// Wave = 1 node; lane = edge-group (lane>>4) x 16B-feat (lane&15). 4 edges concurrent,
// 4-stage named ping-pong (8+ loads in flight). OOB stage -> weight-0 dummy gather of row n.
__global__ __launch_bounds__(512) void k_agg(const unsigned short* __restrict__ xhb,
                                             const float* __restrict__ dinv,
                                             const int* __restrict__ offsets,
                                             const int2* __restrict__ ebuf,
                                             unsigned short* __restrict__ aggb) {
    int t = threadIdx.x;
    int lane = t & 63, wid = t >> 6;
    int bid = blockIdx.x;
    int xcd = bid & 7;
    int b = xcd >> 1, kh = xcd & 1;
    int n = (bid >> 3) * 8 + wid;
    int eg = lane >> 4;        // edge group 0..3
    int fl = lane & 15;        // 16 lanes x 16B = 256B per edge-slice

    const unsigned short* base = xhb + (size_t)b * 256 + kh * 128 + fl * 8;

    int beg = offsets[n], end = offsets[n + 1];
    int iters = (end - beg + 3) >> 2;

    float acc[8] = {0.f, 0.f, 0.f, 0.f, 0.f, 0.f, 0.f, 0.f};

#define LOADE(JJ) (((JJ) < end) ? ebuf[(JJ)] : make_int2(n, 0))
#define GATH(E) (*(const bf16x8*)(base + (size_t)(E).x * 1024))
#define ACC8(E, V)                                                  \
    {                                                               \
        float w = __int_as_float((E).y);                            \
        acc[0] = fmaf(w, bf2f((unsigned short)(V)[0]), acc[0]);     \
        acc[1] = fmaf(w, bf2f((unsigned short)(V)[1]), acc[1]);     \
        acc[2] = fmaf(w, bf2f((unsigned short)(V)[2]), acc[2]);     \
        acc[3] = fmaf(w, bf2f((unsigned short)(V)[3]), acc[3]);     \
        acc[4] = fmaf(w, bf2f((unsigned short)(V)[4]), acc[4]);     \
        acc[5] = fmaf(w, bf2f((unsigned short)(V)[5]), acc[5]);     \
        acc[6] = fmaf(w, bf2f((unsigned short)(V)[6]), acc[6]);     \
        acc[7] = fmaf(w, bf2f((unsigned short)(V)[7]), acc[7]);     \
    }

    // self-loop operand issued early (always needed)
    int2 eS = make_int2(n, 0);
    bf16x8 vS = GATH(eS);
    float di = dinv[n];

    // prologue: 4 stages in flight
    int2 eA = LOADE(beg + eg);
    int2 eB = LOADE(beg + 4 + eg);
    int2 eC = LOADE(beg + 8 + eg);
    int2 eD = LOADE(beg + 12 + eg);
    bf16x8 vA = GATH(eA);
    bf16x8 vB = GATH(eB);
    bf16x8 vC = GATH(eC);
    bf16x8 vD = GATH(eD);

    int it = 0;
    for (; it + 4 <= iters; it += 4) {
        int jn = beg + (it + 4) * 4 + eg;
        int2 nA = LOADE(jn);
        int2 nB = LOADE(jn + 4);
        int2 nC = LOADE(jn + 8);
        int2 nD = LOADE(jn + 12);
        ACC8(eA, vA); eA = nA; vA = GATH(nA);
        ACC8(eB, vB); eB = nB; vB = GATH(nB);
        ACC8(eC, vC); eC = nC; vC = GATH(nC);
        ACC8(eD, vD); eD = nD; vD = GATH(nD);
    }
    int rem = iters - it;
    if (rem >= 1) ACC8(eA, vA);
    if (rem >= 2) ACC8(eB, vB);
    if (rem >= 3) ACC8(eC, vC);

    // cross-group reduce (each fl slice summed over 4 edge-groups)
#pragma unroll
    for (int i = 0; i < 8; ++i) {
        acc[i] += __shfl_xor(acc[i], 16);
        acc[i] += __shfl_xor(acc[i], 32);
    }
    {   // self loop: weight dinv[n]^2 (all lanes add identically post-reduce)
        int2 eW = make_int2(n, __float_as_int(di * di));
        ACC8(eW, vS);
    }
    if (eg == 0) {
        bf16x8 o;
#pragma unroll
        for (int i = 0; i < 8; ++i) o[i] = (short)f2bf(acc[i]);
        *(bf16x8*)(aggb + ((size_t)b * NN + n) * 256 + kh * 128 + fl * 8) = o;
    }
}

// ---------------- MFMA GEMM (40000x256 @ 256^T x 512) + fused LSTM gates ----------------
// 256 thr / 4 waves, __launch_bounds__(256,2). Block = 64 rows x 64 j.
// A staged once in 32KB LDS (swizzled source). Wave owns 16 j x 4 gates: B = 128 VGPR
// loaded once from coalesced Wt2; acc 4mi x 4g; 128 MFMA/wave; one barrier; fused LSTM.
__global__ __launch_bounds__(256, 2) void k_gemm(const unsigned short* __restrict__ aggb,
                                                 const unsigned short* __restrict__ Wt2,
                                                 const float* __restrict__ bcat,
                                                 const float* __restrict__ c_in,
                                                 float* __restrict__ out) {
    __shared__ __align__(16) unsigned short sA[64 * 256];  // 32KB
    int t = threadIdx.x;
    int lane = t & 63, wid = t >> 6;
    int lr = lane & 15, lk = lane >> 4;
    int bid = blockIdx.x;
    int rb = bid >> 1, jb = bid & 1;
    int rowbase = rb * 64;
    int jj = jb * 64 + wid * 16 + lr;  // 0..127

    // stage A: 64 rows x 512B, swizzled global source -> linear LDS
#pragma unroll
    for (int i = 0; i < 8; ++i) {
        int idx = i * 256 + t;
        int row = idx >> 5;
        int cb = (idx & 31) << 4;
        const char* g = (const char*)aggb + (size_t)(rowbase + row) * 512 + (cb ^ ((row & 7) << 4));
        char* l = (char*)sA + (size_t)(i * 256 + wid * 64) * 16;
        GLOAD_LDS16(g, l);
    }

    // B fragments to registers: fully-coalesced Wt2 reads (L2-hot, 32KB/wave)
    bf16x8 breg[4][8];
#pragma unroll
    for (int g = 0; g < 4; ++g)
#pragma unroll
        for (int kb = 0; kb < 8; ++kb)
            breg[g][kb] = *(const bf16x8*)(Wt2 + ((size_t)((g * 8 + kb) * 4 + lk) * 128 + jj) * 8);

    float b_i = bcat[jj], b_f = bcat[128 + jj], b_o = bcat[256 + jj], b_g = bcat[384 + jj];

    __syncthreads();  // A resident

    f32x4 acc[4][4];
#pragma unroll
    for (int mi = 0; mi < 4; ++mi)
#pragma unroll
        for (int g = 0; g < 4; ++g) acc[mi][g] = (f32x4)0.f;

    int aswz = (lr & 7) << 4;
#pragma unroll
    for (int kb = 0; kb < 8; ++kb) {
        int koff = (kb << 6) + (lk << 4);
#pragma unroll
        for (int mi = 0; mi < 4; ++mi) {
            bf16x8 a = *(const bf16x8*)((const char*)sA + (mi * 16 + lr) * 512 + (koff ^ aswz));
            acc[mi][0] = __builtin_amdgcn_mfma_f32_16x16x32_bf16(a, breg[0][kb], acc[mi][0], 0, 0, 0);
            acc[mi][1] = __builtin_amdgcn_mfma_f32_16x16x32_bf16(a, breg[1][kb], acc[mi][1], 0, 0, 0);
            acc[mi][2] = __builtin_amdgcn_mfma_f32_16x16x32_bf16(a, breg[2][kb], acc[mi][2], 0, 0, 0);
            acc[mi][3] = __builtin_amdgcn_mfma_f32_16x16x32_bf16(a, breg[3][kb], acc[mi][3], 0, 0, 0);
        }
    }

    // fused LSTM epilogue: lane holds all 4 gates for (row, jj)
#pragma unroll
    for (int mi = 0; mi < 4; ++mi) {
#pragma unroll
        for (int r = 0; r < 4; ++r) {
            int row = rowbase + mi * 16 + lk * 4 + r;
            size_t o = (size_t)row * 128 + jj;
            float vi = acc[mi][0][r] + b_i;
            float vf = acc[mi][1][r] + b_f;
            float vo = acc[mi][2][r] + b_o;
            float vg = acc[mi][3][r] + b_g;
            float ig = 1.f / (1.f + __expf(-vi));
            float fg = 1.f / (1.f + __expf(-vf));
            float og = 1.f / (1.f + __expf(-vo));
            float gg = 1.f - 2.f / (__expf(2.f * vg) + 1.f);
            float cn = fg * c_in[o] + ig * gg;
            float tc = 1.f - 2.f / (__expf(2.f * cn) + 1.f);
            out[o] = og * tc;
            out[(size_t)NB * NN * 128 + o] = cn;
        }
    }
}

// ---------------- launch ----------------

extern "C" void kernel_launch(void* const* d_in, const int* in_sizes, int n_in,
                              void* d_out, int out_size, void* d_ws, size_t ws_size,
                              hipStream_t stream) {
    const float* x = (const float*)d_in[0];
    const float* h = (const float*)d_in[1];
    const float* c = (const float*)d_in[2];
    const int* ei = (const int*)d_in[3];
    const float* ew = (const float*)d_in[4];
    const float* Wi = (const float*)d_in[5];
    const float* bi = (const float*)d_in[6];
    const float* Wf = (const float*)d_in[7];
    const float* bf = (const float*)d_in[8];
    const float* Wo = (const float*)d_in[9];
    const float* bo = (const float*)d_in[10];
    const float* Wg = (const float*)d_in[11];
    const float* bg = (const float*)d_in[12];
    float* out = (float*)d_out;

    char* ws = (char*)d_ws;
    size_t off = 0;
    auto alloc = [&](size_t bytes) {
        void* p = ws + off;
        off = (off + bytes + 255) & ~(size_t)255;
        return p;
    };
    float* deg = (float*)alloc((size_t)NN * 4);    // 40192B padded; becomes dinv
    int* cnt = (int*)alloc((size_t)NN * 4);        // 40192B
    int* cursor = (int*)alloc((size_t)NN * 4);     // 40192B  (deg,cnt,cursor contiguous)
    int* offsets = (int*)alloc((size_t)(NN + 1) * 4);
    float* bcat = (float*)alloc((size_t)DOUT * 4);
    unsigned short* Wt2 = (unsigned short*)alloc((size_t)DOUT * DIN * 2);
    int2* ebuf = (int2*)alloc((size_t)NE * 8);
    unsigned short* xhb = (unsigned short*)alloc((size_t)NN * 4 * DIN * 2);    // node-major [n][b][k]
    unsigned short* aggb = (unsigned short*)alloc((size_t)NB * NN * DIN * 2);  // batch-major [b*NN+n][k]

    hipMemsetAsync(deg, 0, 3 * 40192, stream);  // deg, cnt, cursor -> 0

    hipLaunchKernelGGL(k_packdeg, dim3(1137), dim3(256), 0, stream,
                       Wi, Wf, Wo, Wg, bi, bf, bo, bg, ei, ew, deg, cnt, Wt2, bcat);
    hipLaunchKernelGGL(k_scancvt, dim3(1251), dim3(1024), 0, stream,
                       deg, cnt, offsets, x, h, xhb);
    hipLaunchKernelGGL(k_fill, dim3(625), dim3(256), 0, stream,
                       ei, ew, deg, offsets, cursor, ebuf);
    hipLaunchKernelGGL(k_agg, dim3(10000), dim3(512), 0, stream,
                       xhb, deg, offsets, ebuf, aggb);
    hipLaunchKernelGGL(k_gemm, dim3(1250), dim3(256), 0, stream,
                       aggb, Wt2, bcat, c, out);
}

// Round 10
// 127.158 us; speedup vs baseline: 1.1240x; 1.0144x over previous
//
#include <hip/hip_runtime.h>
#include <math.h>

#define NB 4
#define NN 10000
#define NE 160000
#define DIN 256   // C+H
#define DOUT 512  // 4H
#define EPAD 310016  // max padded edges: 160000 + 15*10000, rounded up

typedef short bf16x8 __attribute__((ext_vector_type(8)));
typedef float f32x4 __attribute__((ext_vector_type(4)));

#define GLOAD_LDS16(g, l) \
    __builtin_amdgcn_global_load_lds((const __attribute__((address_space(1))) void*)(g), \
                                     (__attribute__((address_space(3))) void*)(l), 16, 0, 0)

__device__ inline unsigned short f2bf(float f) {
    unsigned int u = __float_as_uint(f);
    unsigned int r = (u + 0x7fffu + ((u >> 16) & 1u)) >> 16;
    return (unsigned short)r;
}
__device__ inline float bf2f(unsigned short u) {
    return __uint_as_float(((unsigned int)u) << 16);
}

// ---------------- pack Wt2 + degcnt + cvt (one grid) ----------------
// blocks 0..511: pack Wt2[g][kb][lk][j][8]; 512..1136: degcnt; 1137..6136: x||h -> xhb
__global__ __launch_bounds__(256) void k_packcvt(
        const float* __restrict__ Wi, const float* __restrict__ Wf,
        const float* __restrict__ Wo, const float* __restrict__ Wg,
        const float* __restrict__ bi, const float* __restrict__ bf,
        const float* __restrict__ bo, const float* __restrict__ bg,
        const int* __restrict__ ei, const float* __restrict__ ew,
        const float* __restrict__ x, const float* __restrict__ h,
        float* __restrict__ deg, int* __restrict__ cnt,
        unsigned short* __restrict__ Wt2, float* __restrict__ bcat,
        unsigned short* __restrict__ xhb) {
    int bid = blockIdx.x;
    int t = threadIdx.x;
    if (bid < 512) {
        int i = bid * 256 + t;  // 0..131071
        int e = i & 7;
        int j = (i >> 3) & 127;
        int lk = (i >> 10) & 3;
        int kb = (i >> 12) & 7;
        int g = i >> 15;
        const float* W = (g == 0) ? Wi : (g == 1) ? Wf : (g == 2) ? Wo : Wg;
        Wt2[i] = f2bf(W[(kb * 32 + lk * 8 + e) * 128 + j]);
        if (i < DOUT) {
            int gg = i >> 7, jj = i & 127;
            const float* bb = (gg == 0) ? bi : (gg == 1) ? bf : (gg == 2) ? bo : bg;
            bcat[i] = bb[jj];
        }
    } else if (bid < 1137) {
        int e = (bid - 512) * 256 + t;  // exactly 160000
        int dst = ei[NE + e];
        atomicAdd(&deg[dst], ew[e]);
        atomicAdd(&cnt[dst], 1);
    } else {
        int id = (bid - 1137) * 256 + t;  // 0 .. 1,279,999
        int f8 = id * 8;
        int row = f8 >> 8;        // n*4 + b (node-major)
        int col = f8 & 255;
        int n = row >> 2, b = row & 3;
        const float* src = ((col >> 7) ? h : x) + ((size_t)b * NN + n) * 128 + (col & 127);
        float4 v0 = *(const float4*)src;
        float4 v1 = *(const float4*)(src + 4);
        bf16x8 o;
        o[0] = (short)f2bf(v0.x); o[1] = (short)f2bf(v0.y);
        o[2] = (short)f2bf(v0.z); o[3] = (short)f2bf(v0.w);
        o[4] = (short)f2bf(v1.x); o[5] = (short)f2bf(v1.y);
        o[6] = (short)f2bf(v1.z); o[7] = (short)f2bf(v1.w);
        *(bf16x8*)(xhb + (size_t)f8) = o;
    }
}

// single block: dinv = rsqrt(deg+1); scan of PADDED counts (round up to 16)
__global__ __launch_bounds__(1024) void k_scan(float* __restrict__ deg,
                                               const int* __restrict__ cnt,
                                               int* __restrict__ offsets) {
    int t = threadIdx.x;
    for (int i = t; i < NN; i += 1024) {
        deg[i] = rsqrtf(deg[i] + 1.0f);
    }
    __shared__ int wsum[16];
    int base = t * 10;
    int loc[10];
    int s = 0;
#pragma unroll
    for (int i = 0; i < 10; ++i) {
        int idx = base + i;
        int v = (idx < NN) ? ((cnt[idx] + 15) & ~15) : 0;
        loc[i] = s;
        s += v;
    }
    int lane = t & 63, w = t >> 6;
    int inc = s;
    for (int o = 1; o < 64; o <<= 1) {
        int u = __shfl_up(inc, o);
        if (lane >= o) inc += u;
    }
    if (lane == 63) wsum[w] = inc;
    __syncthreads();
    if (t < 16) {
        int v = wsum[t];
        for (int o = 1; o < 16; o <<= 1) {
            int u = __shfl_up(v, o);
            if (t >= o) v += u;
        }
        wsum[t] = v;
    }
    __syncthreads();
    int wave_excl = (w > 0) ? wsum[w - 1] : 0;
    int thread_excl = wave_excl + inc - s;
#pragma unroll
    for (int i = 0; i < 10; ++i) {
        int idx = base + i;
        if (idx < NN) offsets[idx] = thread_excl + loc[i];
    }
    if (t == 0) offsets[NN] = wsum[15];
}

// fill: ebuf.x = src*2048 (byte offset into node-major xhb rows), ebuf.y = f32 norm
__global__ __launch_bounds__(256) void k_fill(const int* __restrict__ ei,
                                              const float* __restrict__ ew,
                                              const float* __restrict__ dinv,
                                              const int* __restrict__ offsets,
                                              int* cursor, int2* __restrict__ ebuf) {
    int e = blockIdx.x * 256 + threadIdx.x;  // exactly 160000
    int src = ei[e], dst = ei[NE + e];
    float norm = dinv[src] * ew[e] * dinv[dst];
    int pos = offsets[dst] + atomicAdd(&cursor[dst], 1);
    ebuf[pos] = make_int2(src * 2048, __float_as_int(norm));
}

// ---------------- aggregation, XCD-sliced by (batch, k-half), padded windows ----------------
// bid&7 -> (b = xcd>>1, kh = xcd&1): slab = 10000 x 256B = 2.5MB, L2-resident.
// Wave = 1 node; lane = eg(0..3) x fl(0..15). Per 16-edge window: 4 ebuf dwordx2 (imm
// offsets), 4 gathers (1 v_add each), 64 unpack-fma. No bounds checks (padded, zero-filled).
__global__ __launch_bounds__(512) void k_agg(const unsigned short* __restrict__ xhb,
                                             const float* __restrict__ dinv,
                                             const int* __restrict__ offsets,
                                             const int2* __restrict__ ebuf,
                                             unsigned short* __restrict__ aggb) {
    int t = threadIdx.x;
    int lane = t & 63, wid = t >> 6;
    int bid = blockIdx.x;
    int xcd = bid & 7;
    int b = xcd >> 1, kh = xcd & 1;
    int n = (bid >> 3) * 8 + wid;
    int eg = lane >> 4;        // edge slot 0..3 within window quad
    int fl16 = (lane & 15) << 4;  // byte offset of this lane's 16B feature slice

    const char* bb = (const char*)xhb + (b << 9) + (kh << 8);  // uniform per block

    float acc[8] = {0.f, 0.f, 0.f, 0.f, 0.f, 0.f, 0.f, 0.f};

#define ACC8(E, V)                                                  \
    {                                                               \
        float w = __int_as_float((E).y);                            \
        acc[0] = fmaf(w, bf2f((unsigned short)(V)[0]), acc[0]);     \
        acc[1] = fmaf(w, bf2f((unsigned short)(V)[1]), acc[1]);     \
        acc[2] = fmaf(w, bf2f((unsigned short)(V)[2]), acc[2]);     \
        acc[3] = fmaf(w, bf2f((unsigned short)(V)[3]), acc[3]);     \
        acc[4] = fmaf(w, bf2f((unsigned short)(V)[4]), acc[4]);     \
        acc[5] = fmaf(w, bf2f((unsigned short)(V)[5]), acc[5]);     \
        acc[6] = fmaf(w, bf2f((unsigned short)(V)[6]), acc[6]);     \
        acc[7] = fmaf(w, bf2f((unsigned short)(V)[7]), acc[7]);     \
    }

    // self-loop gather issued early (independent)
    bf16x8 vS = *(const bf16x8*)(bb + n * 2048 + fl16);
    float di = dinv[n];

    int beg = offsets[n], end = offsets[n + 1];  // multiples of 16
    const char* ep = (const char*)ebuf + (size_t)beg * 8 + eg * 8;
    for (int j = beg; j < end; j += 16, ep += 128) {
        int2 e0 = *(const int2*)(ep);
        int2 e1 = *(const int2*)(ep + 32);
        int2 e2 = *(const int2*)(ep + 64);
        int2 e3 = *(const int2*)(ep + 96);
        bf16x8 v0 = *(const bf16x8*)(bb + e0.x + fl16);
        bf16x8 v1 = *(const bf16x8*)(bb + e1.x + fl16);
        bf16x8 v2 = *(const bf16x8*)(bb + e2.x + fl16);
        bf16x8 v3 = *(const bf16x8*)(bb + e3.x + fl16);
        ACC8(e0, v0);
        ACC8(e1, v1);
        ACC8(e2, v2);
        ACC8(e3, v3);
    }

    // reduce across the 4 edge slots (lanes sharing fl)
#pragma unroll
    for (int i = 0; i < 8; ++i) {
        acc[i] += __shfl_xor(acc[i], 16);
        acc[i] += __shfl_xor(acc[i], 32);
    }
    {   // self loop: weight dinv[n]^2
        int2 eW = make_int2(0, __float_as_int(di * di));
        ACC8(eW, vS);
    }
    if (eg == 0) {
        bf16x8 o;
#pragma unroll
        for (int i = 0; i < 8; ++i) o[i] = (short)f2bf(acc[i]);
        *(bf16x8*)(aggb + ((size_t)b * NN + n) * 256 + (kh << 7) + (fl16 >> 1)) = o;
    }
}

// ---------------- MFMA GEMM (40000x256 @ 256^T x 512) + fused LSTM gates ----------------
__global__ __launch_bounds__(256, 2) void k_gemm(const unsigned short* __restrict__ aggb,
                                                 const unsigned short* __restrict__ Wt2,
                                                 const float* __restrict__ bcat,
                                                 const float* __restrict__ c_in,
                                                 float* __restrict__ out) {
    __shared__ __align__(16) unsigned short sA[64 * 256];  // 32KB
    int t = threadIdx.x;
    int lane = t & 63, wid = t >> 6;
    int lr = lane & 15, lk = lane >> 4;
    int bid = blockIdx.x;
    int rb = bid >> 1, jb = bid & 1;
    int rowbase = rb * 64;
    int jj = jb * 64 + wid * 16 + lr;  // 0..127

    // stage A: 64 rows x 512B, swizzled global source -> linear LDS
#pragma unroll
    for (int i = 0; i < 8; ++i) {
        int idx = i * 256 + t;
        int row = idx >> 5;
        int cb = (idx & 31) << 4;
        const char* g = (const char*)aggb + (size_t)(rowbase + row) * 512 + (cb ^ ((row & 7) << 4));
        char* l = (char*)sA + (size_t)(i * 256 + wid * 64) * 16;
        GLOAD_LDS16(g, l);
    }

    // B fragments to registers: fully-coalesced Wt2 reads (L2-hot, 32KB/wave)
    bf16x8 breg[4][8];
#pragma unroll
    for (int g = 0; g < 4; ++g)
#pragma unroll
        for (int kb = 0; kb < 8; ++kb)
            breg[g][kb] = *(const bf16x8*)(Wt2 + ((size_t)((g * 8 + kb) * 4 + lk) * 128 + jj) * 8);

    float b_i = bcat[jj], b_f = bcat[128 + jj], b_o = bcat[256 + jj], b_g = bcat[384 + jj];

    __syncthreads();  // A resident

    f32x4 acc[4][4];
#pragma unroll
    for (int mi = 0; mi < 4; ++mi)
#pragma unroll
        for (int g = 0; g < 4; ++g) acc[mi][g] = (f32x4)0.f;

    int aswz = (lr & 7) << 4;
#pragma unroll
    for (int kb = 0; kb < 8; ++kb) {
        int koff = (kb << 6) + (lk << 4);
#pragma unroll
        for (int mi = 0; mi < 4; ++mi) {
            bf16x8 a = *(const bf16x8*)((const char*)sA + (mi * 16 + lr) * 512 + (koff ^ aswz));
            acc[mi][0] = __builtin_amdgcn_mfma_f32_16x16x32_bf16(a, breg[0][kb], acc[mi][0], 0, 0, 0);
            acc[mi][1] = __builtin_amdgcn_mfma_f32_16x16x32_bf16(a, breg[1][kb], acc[mi][1], 0, 0, 0);
            acc[mi][2] = __builtin_amdgcn_mfma_f32_16x16x32_bf16(a, breg[2][kb], acc[mi][2], 0, 0, 0);
            acc[mi][3] = __builtin_amdgcn_mfma_f32_16x16x32_bf16(a, breg[3][kb], acc[mi][3], 0, 0, 0);
        }
    }

    // fused LSTM epilogue: lane holds all 4 gates for (row, jj)
#pragma unroll
    for (int mi = 0; mi < 4; ++mi) {
#pragma unroll
        for (int r = 0; r < 4; ++r) {
            int row = rowbase + mi * 16 + lk * 4 + r;
            size_t o = (size_t)row * 128 + jj;
            float vi = acc[mi][0][r] + b_i;
            float vf = acc[mi][1][r] + b_f;
            float vo = acc[mi][2][r] + b_o;
            float vg = acc[mi][3][r] + b_g;
            float ig = 1.f / (1.f + __expf(-vi));
            float fg = 1.f / (1.f + __expf(-vf));
            float og = 1.f / (1.f + __expf(-vo));
            float gg = 1.f - 2.f / (__expf(2.f * vg) + 1.f);
            float cn = fg * c_in[o] + ig * gg;
            float tc = 1.f - 2.f / (__expf(2.f * cn) + 1.f);
            out[o] = og * tc;
            out[(size_t)NB * NN * 128 + o] = cn;
        }
    }
}

// ---------------- launch ----------------

extern "C" void kernel_launch(void* const* d_in, const int* in_sizes, int n_in,
                              void* d_out, int out_size, void* d_ws, size_t ws_size,
                              hipStream_t stream) {
    const float* x = (const float*)d_in[0];
    const float* h = (const float*)d_in[1];
    const float* c = (const float*)d_in[2];
    const int* ei = (const int*)d_in[3];
    const float* ew = (const float*)d_in[4];
    const float* Wi = (const float*)d_in[5];
    const float* bi = (const float*)d_in[6];
    const float* Wf = (const float*)d_in[7];
    const float* bf = (const float*)d_in[8];
    const float* Wo = (const float*)d_in[9];
    const float* bo = (const float*)d_in[10];
    const float* Wg = (const float*)d_in[11];
    const float* bg = (const float*)d_in[12];
    float* out = (float*)d_out;

    char* ws = (char*)d_ws;
    size_t off = 0;
    auto alloc = [&](size_t bytes) {
        void* p = ws + off;
        off = (off + bytes + 255) & ~(size_t)255;
        return p;
    };
    float* deg = (float*)alloc((size_t)NN * 4);    // 40192B padded; becomes dinv
    int* cnt = (int*)alloc((size_t)NN * 4);        // 40192B
    int* cursor = (int*)alloc((size_t)NN * 4);     // 40192B  (deg,cnt,cursor contiguous)
    int* offsets = (int*)alloc((size_t)(NN + 1) * 4);
    float* bcat = (float*)alloc((size_t)DOUT * 4);
    unsigned short* Wt2 = (unsigned short*)alloc((size_t)DOUT * DIN * 2);
    int2* ebuf = (int2*)alloc((size_t)EPAD * 8);
    unsigned short* xhb = (unsigned short*)alloc((size_t)NN * 4 * DIN * 2);    // node-major [n][b][k]
    unsigned short* aggb = (unsigned short*)alloc((size_t)NB * NN * DIN * 2);  // batch-major [b*NN+n][k]

    hipMemsetAsync(deg, 0, 3 * 40192, stream);          // deg, cnt, cursor -> 0
    hipMemsetAsync(ebuf, 0, (size_t)EPAD * 8, stream);  // pad entries = (0, 0.0f)

    hipLaunchKernelGGL(k_packcvt, dim3(6137), dim3(256), 0, stream,
                       Wi, Wf, Wo, Wg, bi, bf, bo, bg, ei, ew, x, h, deg, cnt, Wt2, bcat, xhb);
    hipLaunchKernelGGL(k_scan, dim3(1), dim3(1024), 0, stream, deg, cnt, offsets);
    hipLaunchKernelGGL(k_fill, dim3(625), dim3(256), 0, stream,
                       ei, ew, deg, offsets, cursor, ebuf);
    hipLaunchKernelGGL(k_agg, dim3(10000), dim3(512), 0, stream,
                       xhb, deg, offsets, ebuf, aggb);
    hipLaunchKernelGGL(k_gemm, dim3(1250), dim3(256), 0, stream,
                       aggb, Wt2, bcat, c, out);
}

// Round 11
// 125.579 us; speedup vs baseline: 1.1381x; 1.0126x over previous
//
#include <hip/hip_runtime.h>
#include <math.h>

#define NB 4
#define NN 10000
#define NE 160000
#define DIN 256   // C+H
#define DOUT 512  // 4H
#define EPAD 310016  // max padded edges: 160000 + 15*10000, rounded up

typedef _Float16 f16x8 __attribute__((ext_vector_type(8)));
typedef _Float16 f16x2 __attribute__((ext_vector_type(2)));
typedef float f32x4 __attribute__((ext_vector_type(4)));

struct hv4 { f16x2 p[4]; };  // 16B = 8 halves as 4 packed pairs

#define GLOAD_LDS16(g, l) \
    __builtin_amdgcn_global_load_lds((const __attribute__((address_space(1))) void*)(g), \
                                     (__attribute__((address_space(3))) void*)(l), 16, 0, 0)

// ---------------- pack Wt2 (f16) + degcnt + cvt x||h -> f16 (one grid) ----------------
// blocks 0..511: pack Wt2[g][kb][lk][j][8]; 512..1136: degcnt; 1137..6136: cvt
__global__ __launch_bounds__(256) void k_packcvt(
        const float* __restrict__ Wi, const float* __restrict__ Wf,
        const float* __restrict__ Wo, const float* __restrict__ Wg,
        const float* __restrict__ bi, const float* __restrict__ bf,
        const float* __restrict__ bo, const float* __restrict__ bg,
        const int* __restrict__ ei, const float* __restrict__ ew,
        const float* __restrict__ x, const float* __restrict__ h,
        float* __restrict__ deg, int* __restrict__ cnt,
        _Float16* __restrict__ Wt2, float* __restrict__ bcat,
        _Float16* __restrict__ xhb) {
    int bid = blockIdx.x;
    int t = threadIdx.x;
    if (bid < 512) {
        int i = bid * 256 + t;  // 0..131071
        int e = i & 7;
        int j = (i >> 3) & 127;
        int lk = (i >> 10) & 3;
        int kb = (i >> 12) & 7;
        int g = i >> 15;
        const float* W = (g == 0) ? Wi : (g == 1) ? Wf : (g == 2) ? Wo : Wg;
        Wt2[i] = (_Float16)W[(kb * 32 + lk * 8 + e) * 128 + j];
        if (i < DOUT) {
            int gg = i >> 7, jj = i & 127;
            const float* bb = (gg == 0) ? bi : (gg == 1) ? bf : (gg == 2) ? bo : bg;
            bcat[i] = bb[jj];
        }
    } else if (bid < 1137) {
        int e = (bid - 512) * 256 + t;  // exactly 160000
        int dst = ei[NE + e];
        atomicAdd(&deg[dst], ew[e]);
        atomicAdd(&cnt[dst], 1);
    } else {
        int id = (bid - 1137) * 256 + t;  // 0 .. 1,279,999
        int f8 = id * 8;
        int row = f8 >> 8;        // n*4 + b (node-major)
        int col = f8 & 255;
        int n = row >> 2, b = row & 3;
        const float* src = ((col >> 7) ? h : x) + ((size_t)b * NN + n) * 128 + (col & 127);
        float4 v0 = *(const float4*)src;
        float4 v1 = *(const float4*)(src + 4);
        f16x8 o;
        o[0] = (_Float16)v0.x; o[1] = (_Float16)v0.y;
        o[2] = (_Float16)v0.z; o[3] = (_Float16)v0.w;
        o[4] = (_Float16)v1.x; o[5] = (_Float16)v1.y;
        o[6] = (_Float16)v1.z; o[7] = (_Float16)v1.w;
        *(f16x8*)(xhb + (size_t)f8) = o;
    }
}

// single block: dinv = rsqrt(deg+1); scan of PADDED counts (round up to 16)
__global__ __launch_bounds__(1024) void k_scan(float* __restrict__ deg,
                                               const int* __restrict__ cnt,
                                               int* __restrict__ offsets) {
    int t = threadIdx.x;
    for (int i = t; i < NN; i += 1024) {
        deg[i] = rsqrtf(deg[i] + 1.0f);
    }
    __shared__ int wsum[16];
    int base = t * 10;
    int loc[10];
    int s = 0;
#pragma unroll
    for (int i = 0; i < 10; ++i) {
        int idx = base + i;
        int v = (idx < NN) ? ((cnt[idx] + 15) & ~15) : 0;
        loc[i] = s;
        s += v;
    }
    int lane = t & 63, w = t >> 6;
    int inc = s;
    for (int o = 1; o < 64; o <<= 1) {
        int u = __shfl_up(inc, o);
        if (lane >= o) inc += u;
    }
    if (lane == 63) wsum[w] = inc;
    __syncthreads();
    if (t < 16) {
        int v = wsum[t];
        for (int o = 1; o < 16; o <<= 1) {
            int u = __shfl_up(v, o);
            if (t >= o) v += u;
        }
        wsum[t] = v;
    }
    __syncthreads();
    int wave_excl = (w > 0) ? wsum[w - 1] : 0;
    int thread_excl = wave_excl + inc - s;
#pragma unroll
    for (int i = 0; i < 10; ++i) {
        int idx = base + i;
        if (idx < NN) offsets[idx] = thread_excl + loc[i];
    }
    if (t == 0) offsets[NN] = wsum[15];
}

// fill: ebuf.x = src*2048 (byte offset), ebuf.y = norm as duplicated f16x2
__global__ __launch_bounds__(256) void k_fill(const int* __restrict__ ei,
                                              const float* __restrict__ ew,
                                              const float* __restrict__ dinv,
                                              const int* __restrict__ offsets,
                                              int* cursor, int2* __restrict__ ebuf) {
    int e = blockIdx.x * 256 + threadIdx.x;  // exactly 160000
    int src = ei[e], dst = ei[NE + e];
    float norm = dinv[src] * ew[e] * dinv[dst];
    unsigned short hw;
    {
        _Float16 hnorm = (_Float16)norm;
        hw = __builtin_bit_cast(unsigned short, hnorm);
    }
    int wpair = (int)hw | ((int)hw << 16);
    int pos = offsets[dst] + atomicAdd(&cursor[dst], 1);
    ebuf[pos] = make_int2(src * 2048, wpair);
}

// ---------------- aggregation: XCD-sliced by (batch, k-half), packed f16 fma ----------------
// bid&7 -> (b = xcd>>1, kh = xcd&1): slab = 10000 x 256B = 2.5MB, L2-resident.
// Wave = 1 node; lane = eg(0..3) x fl(0..15). Per 16-edge window: 4 ebuf dwordx2 (imm
// offsets), 4 x 16B gathers, 16 v_pk_fma_f16. Padded windows -> no bounds checks.
__global__ __launch_bounds__(512) void k_agg(const _Float16* __restrict__ xhb,
                                             const float* __restrict__ dinv,
                                             const int* __restrict__ offsets,
                                             const int2* __restrict__ ebuf,
                                             _Float16* __restrict__ aggb) {
    int t = threadIdx.x;
    int lane = t & 63, wid = t >> 6;
    int bid = blockIdx.x;
    int xcd = bid & 7;
    int b = xcd >> 1, kh = xcd & 1;
    int n = (bid >> 3) * 8 + wid;
    int eg = lane >> 4;           // edge slot 0..3 within window quad
    int fl16 = (lane & 15) << 4;  // byte offset of this lane's 16B feature slice

    const char* bb = (const char*)xhb + (b << 9) + (kh << 8);  // uniform per block

    f16x2 pac0 = (f16x2)0, pac1 = (f16x2)0, pac2 = (f16x2)0, pac3 = (f16x2)0;

#define ACCH(E, V)                                          \
    {                                                       \
        f16x2 w2 = __builtin_bit_cast(f16x2, (E).y);        \
        pac0 = (V).p[0] * w2 + pac0;                        \
        pac1 = (V).p[1] * w2 + pac1;                        \
        pac2 = (V).p[2] * w2 + pac2;                        \
        pac3 = (V).p[3] * w2 + pac3;                        \
    }

    // self-loop gather issued early (independent)
    hv4 vS = *(const hv4*)(bb + n * 2048 + fl16);
    float di = dinv[n];

    int beg = offsets[n], end = offsets[n + 1];  // multiples of 16
    const char* ep = (const char*)ebuf + (size_t)beg * 8 + eg * 8;
    for (int j = beg; j < end; j += 16, ep += 128) {
        int2 e0 = *(const int2*)(ep);
        int2 e1 = *(const int2*)(ep + 32);
        int2 e2 = *(const int2*)(ep + 64);
        int2 e3 = *(const int2*)(ep + 96);
        hv4 v0 = *(const hv4*)(bb + e0.x + fl16);
        hv4 v1 = *(const hv4*)(bb + e1.x + fl16);
        hv4 v2 = *(const hv4*)(bb + e2.x + fl16);
        hv4 v3 = *(const hv4*)(bb + e3.x + fl16);
        ACCH(e0, v0);
        ACCH(e1, v1);
        ACCH(e2, v2);
        ACCH(e3, v3);
    }

    // convert to f32, reduce across the 4 edge slots (lanes sharing fl)
    float a[8];
    a[0] = (float)pac0[0]; a[1] = (float)pac0[1];
    a[2] = (float)pac1[0]; a[3] = (float)pac1[1];
    a[4] = (float)pac2[0]; a[5] = (float)pac2[1];
    a[6] = (float)pac3[0]; a[7] = (float)pac3[1];
#pragma unroll
    for (int i = 0; i < 8; ++i) {
        a[i] += __shfl_xor(a[i], 16);
        a[i] += __shfl_xor(a[i], 32);
    }
    {   // self loop in f32: weight dinv[n]^2
        float wl = di * di;
        a[0] = fmaf(wl, (float)vS.p[0][0], a[0]);
        a[1] = fmaf(wl, (float)vS.p[0][1], a[1]);
        a[2] = fmaf(wl, (float)vS.p[1][0], a[2]);
        a[3] = fmaf(wl, (float)vS.p[1][1], a[3]);
        a[4] = fmaf(wl, (float)vS.p[2][0], a[4]);
        a[5] = fmaf(wl, (float)vS.p[2][1], a[5]);
        a[6] = fmaf(wl, (float)vS.p[3][0], a[6]);
        a[7] = fmaf(wl, (float)vS.p[3][1], a[7]);
    }
    if (eg == 0) {
        f16x8 o;
#pragma unroll
        for (int i = 0; i < 8; ++i) o[i] = (_Float16)a[i];
        *(f16x8*)(aggb + ((size_t)b * NN + n) * 256 + (kh << 7) + (fl16 >> 1)) = o;
    }
}

// ---------------- MFMA GEMM f16 (40000x256 @ 256^T x 512) + fused LSTM gates ----------------
__global__ __launch_bounds__(256, 2) void k_gemm(const _Float16* __restrict__ aggb,
                                                 const _Float16* __restrict__ Wt2,
                                                 const float* __restrict__ bcat,
                                                 const float* __restrict__ c_in,
                                                 float* __restrict__ out) {
    __shared__ __align__(16) _Float16 sA[64 * 256];  // 32KB
    int t = threadIdx.x;
    int lane = t & 63, wid = t >> 6;
    int lr = lane & 15, lk = lane >> 4;
    int bid = blockIdx.x;
    int rb = bid >> 1, jb = bid & 1;
    int rowbase = rb * 64;
    int jj = jb * 64 + wid * 16 + lr;  // 0..127

    // stage A: 64 rows x 512B, swizzled global source -> linear LDS
#pragma unroll
    for (int i = 0; i < 8; ++i) {
        int idx = i * 256 + t;
        int row = idx >> 5;
        int cb = (idx & 31) << 4;
        const char* g = (const char*)aggb + (size_t)(rowbase + row) * 512 + (cb ^ ((row & 7) << 4));
        char* l = (char*)sA + (size_t)(i * 256 + wid * 64) * 16;
        GLOAD_LDS16(g, l);
    }

    // B fragments to registers: fully-coalesced Wt2 reads (L2-hot, 32KB/wave)
    f16x8 breg[4][8];
#pragma unroll
    for (int g = 0; g < 4; ++g)
#pragma unroll
        for (int kb = 0; kb < 8; ++kb)
            breg[g][kb] = *(const f16x8*)(Wt2 + ((size_t)((g * 8 + kb) * 4 + lk) * 128 + jj) * 8);

    float b_i = bcat[jj], b_f = bcat[128 + jj], b_o = bcat[256 + jj], b_g = bcat[384 + jj];

    __syncthreads();  // A resident

    f32x4 acc[4][4];
#pragma unroll
    for (int mi = 0; mi < 4; ++mi)
#pragma unroll
        for (int g = 0; g < 4; ++g) acc[mi][g] = (f32x4)0.f;

    int aswz = (lr & 7) << 4;
#pragma unroll
    for (int kb = 0; kb < 8; ++kb) {
        int koff = (kb << 6) + (lk << 4);
#pragma unroll
        for (int mi = 0; mi < 4; ++mi) {
            f16x8 a = *(const f16x8*)((const char*)sA + (mi * 16 + lr) * 512 + (koff ^ aswz));
            acc[mi][0] = __builtin_amdgcn_mfma_f32_16x16x32_f16(a, breg[0][kb], acc[mi][0], 0, 0, 0);
            acc[mi][1] = __builtin_amdgcn_mfma_f32_16x16x32_f16(a, breg[1][kb], acc[mi][1], 0, 0, 0);
            acc[mi][2] = __builtin_amdgcn_mfma_f32_16x16x32_f16(a, breg[2][kb], acc[mi][2], 0, 0, 0);
            acc[mi][3] = __builtin_amdgcn_mfma_f32_16x16x32_f16(a, breg[3][kb], acc[mi][3], 0, 0, 0);
        }
    }

    // fused LSTM epilogue: lane holds all 4 gates for (row, jj)
#pragma unroll
    for (int mi = 0; mi < 4; ++mi) {
#pragma unroll
        for (int r = 0; r < 4; ++r) {
            int row = rowbase + mi * 16 + lk * 4 + r;
            size_t o = (size_t)row * 128 + jj;
            float vi = acc[mi][0][r] + b_i;
            float vf = acc[mi][1][r] + b_f;
            float vo = acc[mi][2][r] + b_o;
            float vg = acc[mi][3][r] + b_g;
            float ig = 1.f / (1.f + __expf(-vi));
            float fg = 1.f / (1.f + __expf(-vf));
            float og = 1.f / (1.f + __expf(-vo));
            float gg = 1.f - 2.f / (__expf(2.f * vg) + 1.f);
            float cn = fg * c_in[o] + ig * gg;
            float tc = 1.f - 2.f / (__expf(2.f * cn) + 1.f);
            out[o] = og * tc;
            out[(size_t)NB * NN * 128 + o] = cn;
        }
    }
}

// ---------------- launch ----------------

extern "C" void kernel_launch(void* const* d_in, const int* in_sizes, int n_in,
                              void* d_out, int out_size, void* d_ws, size_t ws_size,
                              hipStream_t stream) {
    const float* x = (const float*)d_in[0];
    const float* h = (const float*)d_in[1];
    const float* c = (const float*)d_in[2];
    const int* ei = (const int*)d_in[3];
    const float* ew = (const float*)d_in[4];
    const float* Wi = (const float*)d_in[5];
    const float* bi = (const float*)d_in[6];
    const float* Wf = (const float*)d_in[7];
    const float* bf = (const float*)d_in[8];
    const float* Wo = (const float*)d_in[9];
    const float* bo = (const float*)d_in[10];
    const float* Wg = (const float*)d_in[11];
    const float* bg = (const float*)d_in[12];
    float* out = (float*)d_out;

    char* ws = (char*)d_ws;
    size_t off = 0;
    auto alloc = [&](size_t bytes) {
        void* p = ws + off;
        off = (off + bytes + 255) & ~(size_t)255;
        return p;
    };
    float* deg = (float*)alloc((size_t)NN * 4);    // 40192B padded; becomes dinv
    int* cnt = (int*)alloc((size_t)NN * 4);        // 40192B
    int* cursor = (int*)alloc((size_t)NN * 4);     // 40192B  (deg,cnt,cursor contiguous)
    int* offsets = (int*)alloc((size_t)(NN + 1) * 4);
    float* bcat = (float*)alloc((size_t)DOUT * 4);
    _Float16* Wt2 = (_Float16*)alloc((size_t)DOUT * DIN * 2);
    int2* ebuf = (int2*)alloc((size_t)EPAD * 8);
    _Float16* xhb = (_Float16*)alloc((size_t)NN * 4 * DIN * 2);    // node-major [n][b][k]
    _Float16* aggb = (_Float16*)alloc((size_t)NB * NN * DIN * 2);  // batch-major [b*NN+n][k]

    hipMemsetAsync(deg, 0, 3 * 40192, stream);          // deg, cnt, cursor -> 0
    hipMemsetAsync(ebuf, 0, (size_t)EPAD * 8, stream);  // pad entries = (0, 0.0h pair)

    hipLaunchKernelGGL(k_packcvt, dim3(6137), dim3(256), 0, stream,
                       Wi, Wf, Wo, Wg, bi, bf, bo, bg, ei, ew, x, h, deg, cnt, Wt2, bcat, xhb);
    hipLaunchKernelGGL(k_scan, dim3(1), dim3(1024), 0, stream, deg, cnt, offsets);
    hipLaunchKernelGGL(k_fill, dim3(625), dim3(256), 0, stream,
                       ei, ew, deg, offsets, cursor, ebuf);
    hipLaunchKernelGGL(k_agg, dim3(10000), dim3(512), 0, stream,
                       xhb, deg, offsets, ebuf, aggb);
    hipLaunchKernelGGL(k_gemm, dim3(1250), dim3(256), 0, stream,
                       aggb, Wt2, bcat, c, out);
}